// Round 2
// baseline (1658.005 us; speedup 1.0000x reference)
//
#include <hip/hip_runtime.h>
#include <hip/hip_bf16.h>

// ---------------------------------------------------------------------------
// SharedSpecialistMoEFFN on MI355X (gfx950) — round 2
//
// R1 post-mortem: GEMMs latency-bound (MfmaUtil 16%, occ 29%) — too few
// co-resident blocks per CU for the 2-barrier K-loop. Fixes this round:
//   * merged launches: FFN1/FFN2 each cover shared (z=0) + 8 experts (z=1..8)
//   * BK=64 (32 KB LDS, 5 blocks/CU cap): 2x MFMA per latency window,
//     half the barrier count. XOR k-chunk swizzle on the staging lane map
//     keeps ds_read_b128 at 2-way banks (free) at the 128 B row stride.
//   * no atomics: expert FFN2 stores gathered-order Yexp; combine kernel
//     applies routing weights via an inverse map.
// Precision: fp16 MFMA everywhere (R1 absmax 1.6e-2 vs 6.8e-2 threshold).
// Workspace ~370 MB (Yexp aliases w1t, dead after FFN1).
// ---------------------------------------------------------------------------

#define D_MODEL 1024
#define D_FF    4096
#define N_EXP   8
#define T_TOK   8192
#define BK      64

typedef _Float16 half8  __attribute__((ext_vector_type(8)));
typedef _Float16 half4v __attribute__((ext_vector_type(4)));
typedef float    floatx4 __attribute__((ext_vector_type(4)));

__device__ __forceinline__ float gelu_exact(float x) {
  return 0.5f * x * (1.0f + erff(x * 0.70710678118654752f));
}

__device__ __forceinline__ void gld_lds16(const _Float16* g, _Float16* l) {
  __builtin_amdgcn_global_load_lds(
      (const __attribute__((address_space(1))) void*)g,
      (__attribute__((address_space(3))) void*)l, 16, 0, 0);
}

// ---------------------------------------------------------------- converts
__global__ void convert_f32_f16(const float* __restrict__ src,
                                _Float16* __restrict__ dst, int n4) {
  int i = blockIdx.x * blockDim.x + threadIdx.x;
  if (i >= n4) return;
  float4 v = ((const float4*)src)[i];
  half4v h;
  h[0] = (_Float16)v.x; h[1] = (_Float16)v.y;
  h[2] = (_Float16)v.z; h[3] = (_Float16)v.w;
  ((half4v*)dst)[i] = h;
}

// z=0: shared weight, z>=1: expert z-1.  src fp32 [R][C] -> dst fp16 [C][R]
__global__ void transpose_convert9(const float* __restrict__ srcSh,
                                   const float* __restrict__ srcEx,
                                   _Float16* __restrict__ dst, int R, int C) {
  const size_t msz = (size_t)R * C;
  const float* src = (blockIdx.z == 0) ? srcSh : srcEx + msz * (blockIdx.z - 1);
  _Float16* d = dst + msz * blockIdx.z;
  __shared__ float tile[32][33];
  int c0 = blockIdx.x * 32, r0 = blockIdx.y * 32;
  int tx = threadIdx.x, ty = threadIdx.y;   // block (32, 8)
#pragma unroll
  for (int i = 0; i < 4; ++i)
    tile[ty + i * 8][tx] = src[(size_t)(r0 + ty + i * 8) * C + c0 + tx];
  __syncthreads();
#pragma unroll
  for (int i = 0; i < 4; ++i)
    d[(size_t)(c0 + ty + i * 8) * R + r0 + tx] = (_Float16)tile[tx][ty + i * 8];
}

// ---------------------------------------------------------------- router
__global__ void router_kernel(const float* __restrict__ x,
                              const float* __restrict__ rw,
                              const float* __restrict__ rb,
                              int* __restrict__ sel_idx,
                              float* __restrict__ sel_w,
                              int* __restrict__ counts) {
  int lane = threadIdx.x & 63;
  int t = blockIdx.x * 4 + (threadIdx.x >> 6);
  const float* xr = x + (size_t)t * D_MODEL;
  float acc[N_EXP];
#pragma unroll
  for (int e = 0; e < N_EXP; ++e) acc[e] = 0.f;
  for (int k = lane; k < D_MODEL; k += 64) {
    float xv = xr[k];
    const float* w = rw + (size_t)k * N_EXP;
#pragma unroll
    for (int e = 0; e < N_EXP; ++e) acc[e] += xv * w[e];
  }
#pragma unroll
  for (int off = 32; off > 0; off >>= 1) {
#pragma unroll
    for (int e = 0; e < N_EXP; ++e)
      acc[e] += __shfl_down(acc[e], off, 64);
  }
  if (lane == 0) {
    float mx = -1e30f;
#pragma unroll
    for (int e = 0; e < N_EXP; ++e) { acc[e] += rb[e]; mx = fmaxf(mx, acc[e]); }
    float p[N_EXP], s = 0.f;
#pragma unroll
    for (int e = 0; e < N_EXP; ++e) { p[e] = expf(acc[e] - mx); s += p[e]; }
    float inv = 1.f / s;
#pragma unroll
    for (int e = 0; e < N_EXP; ++e) p[e] *= inv;
    int i0 = 0; float p0 = p[0];
#pragma unroll
    for (int e = 1; e < N_EXP; ++e) if (p[e] > p0) { p0 = p[e]; i0 = e; }
    int i1 = -1; float p1 = -1.f;
#pragma unroll
    for (int e = 0; e < N_EXP; ++e)
      if (e != i0 && p[e] > p1) { p1 = p[e]; i1 = e; }
    float s2 = p0 + p1 + 1e-9f;
    sel_idx[2 * t] = i0; sel_idx[2 * t + 1] = i1;
    sel_w[2 * t] = p0 / s2; sel_w[2 * t + 1] = p1 / s2;
    atomicAdd(&counts[i0 * 32], 1);
    atomicAdd(&counts[i1 * 32], 1);
  }
}

__global__ void scan_kernel(const int* __restrict__ counts,
                            int* __restrict__ offsets,
                            int* __restrict__ cursor) {
  if (threadIdx.x == 0) {
    int s = 0;
    for (int e = 0; e < N_EXP; ++e) {
      offsets[e] = s; cursor[e * 32] = s; s += counts[e * 32];
    }
    offsets[N_EXP] = s;
  }
}

__global__ void assign_kernel(const int* __restrict__ sel_idx,
                              int* __restrict__ cursor,
                              int* __restrict__ rows,
                              int* __restrict__ inv) {
  int t = blockIdx.x * blockDim.x + threadIdx.x;
  if (t >= T_TOK) return;
#pragma unroll
  for (int k = 0; k < 2; ++k) {
    int e = sel_idx[2 * t + k];
    int pos = atomicAdd(&cursor[e * 32], 1);
    rows[pos] = t;
    inv[2 * t + k] = pos;
  }
}

// ---------------------------------------------------------------- GEMM
// PHASE 1: FFN1  K=1024, N=4096.  z=0: H[m]=gelu(xb[m]@W1sh+b); z>=1:
//          H[T+offs+m]=gelu(xb[rows[offs+m]]@W1e+b).   fp16 stores.
// PHASE 2: FFN2  K=4096, N=1024.  z=0: out[m]=H[m]@W2sh+b (fp32); z>=1:
//          Yexp[offs+m]=H[T+offs+m]@W2e+b (fp32, gathered order).
// 128x128 tile, BK=64, 256 thr (2x2 waves of 64x64), XOR-swizzled staging.
template <int PHASE>
__global__ __launch_bounds__(256, 4) void gemm_kernel(
    const _Float16* __restrict__ A, const _Float16* __restrict__ Wt,
    const float* __restrict__ biasSh, const float* __restrict__ biasEx,
    _Float16* __restrict__ Hout, float* __restrict__ out,
    float* __restrict__ Yexp, const int* __restrict__ rows,
    const int* __restrict__ counts, const int* __restrict__ offsets) {
  constexpr int K = (PHASE == 1) ? D_MODEL : D_FF;
  constexpr int N = (PHASE == 1) ? D_FF : D_MODEL;
  const int z = blockIdx.z;
  int M = T_TOK, offs = 0;
  if (z > 0) {
    M = counts[(z - 1) * 32];
    offs = offsets[z - 1];
    if ((int)blockIdx.y * 128 >= M) return;   // uniform early-exit
  }
  const int tid = threadIdx.x, lane = tid & 63, wid = tid >> 6;
  const int m0 = blockIdx.y * 128, n0 = blockIdx.x * 128;
  const _Float16* Wz = Wt + (size_t)z * N * K;

  __shared__ __align__(16) _Float16 As[128 * BK];  // [m][k], k-chunks swizzled
  __shared__ __align__(16) _Float16 Bs[128 * BK];  // [n][k]

  // staging: 16 chunk-groups of 8 rows x 128 B; wave w fills groups 4w..4w+3.
  // lane i -> row sub=i>>3 of the group, physical 16B slot p=i&7 holding
  // GLOBAL k-chunk g = p ^ (row&7)  (XOR swizzle; row&7 == sub).
  const int sub = lane >> 3, p = lane & 7, g = p ^ sub;
  const _Float16* aS[4];
  const _Float16* bS[4];
  _Float16 *ldsA[4], *ldsB[4];
#pragma unroll
  for (int j = 0; j < 4; ++j) {
    const int c = wid * 4 + j;
    const int rA = m0 + c * 8 + sub;
    size_t gRow;
    if constexpr (PHASE == 1) {
      gRow = (z == 0) ? (size_t)rA
                      : (size_t)rows[offs + (rA < M ? rA : M - 1)];
    } else {
      gRow = (z == 0) ? (size_t)rA
                      : (size_t)(T_TOK + offs + (rA < M ? rA : M - 1));
    }
    aS[j] = A + gRow * K + g * 8;
    bS[j] = Wz + (size_t)(n0 + c * 8 + sub) * K + g * 8;
    ldsA[j] = As + c * 512;   // wave-uniform; HW adds lane*16B
    ldsB[j] = Bs + c * 512;
  }

  floatx4 acc[4][4] = {};
  const int wm = wid >> 1, wn = wid & 1;
  const int lr = lane & 15, qd = lane >> 4;

  for (int kt = 0; kt < K; kt += BK) {
    __syncthreads();
#pragma unroll
    for (int j = 0; j < 4; ++j) { gld_lds16(aS[j], ldsA[j]); gld_lds16(bS[j], ldsB[j]); }
#pragma unroll
    for (int j = 0; j < 4; ++j) { aS[j] += BK; bS[j] += BK; }
    asm volatile("s_waitcnt vmcnt(0)" ::: "memory");
    __syncthreads();
#pragma unroll
    for (int h = 0; h < 2; ++h) {
      half8 af[4], bf[4];
#pragma unroll
      for (int mi = 0; mi < 4; ++mi) {
        const int r = wm * 64 + mi * 16 + lr;
        const int slot = (h * 4 + qd) ^ (r & 7);
        af[mi] = *(const half8*)(As + r * BK + slot * 8);
      }
#pragma unroll
      for (int ni = 0; ni < 4; ++ni) {
        const int r = wn * 64 + ni * 16 + lr;
        const int slot = (h * 4 + qd) ^ (r & 7);
        bf[ni] = *(const half8*)(Bs + r * BK + slot * 8);
      }
#pragma unroll
      for (int mi = 0; mi < 4; ++mi)
#pragma unroll
        for (int ni = 0; ni < 4; ++ni)
          acc[mi][ni] = __builtin_amdgcn_mfma_f32_16x16x32_f16(
              af[mi], bf[ni], acc[mi][ni], 0, 0, 0);
    }
  }

  // epilogue: C/D layout col=lane&15, row=quad*4+reg (R1-verified)
  const float* be = (z == 0) ? biasSh : biasEx + (size_t)(z - 1) * N;
#pragma unroll
  for (int mi = 0; mi < 4; ++mi) {
#pragma unroll
    for (int ni = 0; ni < 4; ++ni) {
      floatx4 v = acc[mi][ni];
#pragma unroll
      for (int r4 = 0; r4 < 4; ++r4) {
        const int lrow = m0 + wm * 64 + mi * 16 + qd * 4 + r4;  // row in segment
        const int col = n0 + wn * 64 + ni * 16 + lr;
        const float val = v[r4] + be[col];
        if constexpr (PHASE == 1) {
          if (z == 0) {
            Hout[(size_t)lrow * N + col] = (_Float16)gelu_exact(val);
          } else if (lrow < M) {
            Hout[(size_t)(T_TOK + offs + lrow) * N + col] =
                (_Float16)gelu_exact(val);
          }
        } else {
          if (z == 0) {
            out[(size_t)lrow * N + col] = val;
          } else if (lrow < M) {
            Yexp[(size_t)(offs + lrow) * N + col] = val;
          }
        }
      }
    }
  }
}

// ---------------------------------------------------------------- combine
// out[t] = out[t] (shared FFN2) + w0*Yexp[p0] + w1*Yexp[p1]
__global__ void combine_kernel(float* __restrict__ out,
                               const float* __restrict__ Yexp,
                               const int* __restrict__ inv,
                               const float* __restrict__ selw) {
  const int t = blockIdx.x;
  const int c = threadIdx.x * 4;
  const int p0 = inv[2 * t], p1 = inv[2 * t + 1];
  const float w0 = selw[2 * t], w1 = selw[2 * t + 1];
  float4 o = *(float4*)(out + (size_t)t * D_MODEL + c);
  const float4 a = *(const float4*)(Yexp + (size_t)p0 * D_MODEL + c);
  const float4 b = *(const float4*)(Yexp + (size_t)p1 * D_MODEL + c);
  o.x += w0 * a.x + w1 * b.x;
  o.y += w0 * a.y + w1 * b.y;
  o.z += w0 * a.z + w1 * b.z;
  o.w += w0 * a.w + w1 * b.w;
  *(float4*)(out + (size_t)t * D_MODEL + c) = o;
}

// ---------------------------------------------------------------- launch
extern "C" void kernel_launch(void* const* d_in, const int* in_sizes, int n_in,
                              void* d_out, int out_size, void* d_ws,
                              size_t ws_size, hipStream_t stream) {
  const float* x   = (const float*)d_in[0];
  const float* sw1 = (const float*)d_in[1];
  const float* sb1 = (const float*)d_in[2];
  const float* sw2 = (const float*)d_in[3];
  const float* sb2 = (const float*)d_in[4];
  const float* rw  = (const float*)d_in[5];
  const float* rb  = (const float*)d_in[6];
  const float* ew1 = (const float*)d_in[7];
  const float* eb1 = (const float*)d_in[8];
  const float* ew2 = (const float*)d_in[9];
  const float* eb2 = (const float*)d_in[10];
  float* out = (float*)d_out;

  char* ws = (char*)d_ws;
  size_t off = 0;
  auto alloc = [&](size_t bytes) {
    void* p = ws + off;
    off += (bytes + 255) & ~(size_t)255;
    return p;
  };
  _Float16* xb  = (_Float16*)alloc((size_t)T_TOK * D_MODEL * 2);        // 16 MB
  _Float16* w2t = (_Float16*)alloc((size_t)9 * D_MODEL * D_FF * 2);     // 72 MB
  _Float16* H   = (_Float16*)alloc((size_t)3 * T_TOK * D_FF * 2);       // 201 MB
  _Float16* w1t = (_Float16*)alloc((size_t)9 * D_FF * D_MODEL * 2);     // 72 MB
  float* Yexp   = (float*)w1t;  // alias: w1t dead after FFN1, Yexp 67 MB
  int*   sel_idx = (int*)alloc((size_t)T_TOK * 2 * 4);
  float* sel_w   = (float*)alloc((size_t)T_TOK * 2 * 4);
  int*   rows    = (int*)alloc((size_t)2 * T_TOK * 4);
  int*   inv     = (int*)alloc((size_t)2 * T_TOK * 4);
  int*   counts  = (int*)alloc(N_EXP * 32 * 4);
  int*   offsets = (int*)alloc(16 * 4);
  int*   cursor  = (int*)alloc(N_EXP * 32 * 4);
  (void)ws_size; (void)in_sizes; (void)n_in; (void)out_size;

  hipMemsetAsync(counts, 0, N_EXP * 32 * 4, stream);

  convert_f32_f16<<<(T_TOK * D_MODEL / 4 + 255) / 256, 256, 0, stream>>>(
      x, xb, T_TOK * D_MODEL / 4);
  dim3 tb(32, 8);
  // W1: [1024][4096] -> [4096][1024];  W2: [4096][1024] -> [1024][4096]
  transpose_convert9<<<dim3(D_FF / 32, D_MODEL / 32, 9), tb, 0, stream>>>(
      sw1, ew1, w1t, D_MODEL, D_FF);
  transpose_convert9<<<dim3(D_MODEL / 32, D_FF / 32, 9), tb, 0, stream>>>(
      sw2, ew2, w2t, D_FF, D_MODEL);

  router_kernel<<<T_TOK / 4, 256, 0, stream>>>(x, rw, rb, sel_idx, sel_w, counts);
  scan_kernel<<<1, 64, 0, stream>>>(counts, offsets, cursor);
  assign_kernel<<<T_TOK / 256, 256, 0, stream>>>(sel_idx, cursor, rows, inv);

  gemm_kernel<1><<<dim3(D_FF / 128, T_TOK / 128, 9), 256, 0, stream>>>(
      xb, w1t, sb1, eb1, H, nullptr, nullptr, rows, counts, offsets);
  gemm_kernel<2><<<dim3(D_MODEL / 128, T_TOK / 128, 9), 256, 0, stream>>>(
      H, w2t, sb2, eb2, nullptr, out, Yexp, rows, counts, offsets);

  combine_kernel<<<T_TOK, 256, 0, stream>>>(out, Yexp, inv, sel_w);
}

// Round 3
// 1075.102 us; speedup vs baseline: 1.5422x; 1.5422x over previous
//
#include <hip/hip_runtime.h>
#include <hip/hip_bf16.h>

// ---------------------------------------------------------------------------
// SharedSpecialistMoEFFN on MI355X (gfx950) — round 3
//
// R2 post-mortem: __launch_bounds__(256,4) capped unified VGPR+AGPR at 128;
// acc(64 AGPR) + frags(16) + 16 pointer regs overflowed -> scratch spill in
// the K-loop (~1 GB of spill stores = the observed WRITE_SIZE 997 MB).
// R3: bounds(256,3) (170-reg cap, as R1 which didn't spill) + scalarized
// staging pointers. Keep: BK=64, XOR k-chunk swizzle (bank conflicts were 0),
// merged shared+expert z-grid, atomic-free combine.
// ---------------------------------------------------------------------------

#define D_MODEL 1024
#define D_FF    4096
#define N_EXP   8
#define T_TOK   8192
#define BK      64

typedef _Float16 half8  __attribute__((ext_vector_type(8)));
typedef _Float16 half4v __attribute__((ext_vector_type(4)));
typedef float    floatx4 __attribute__((ext_vector_type(4)));

__device__ __forceinline__ float gelu_exact(float x) {
  return 0.5f * x * (1.0f + erff(x * 0.70710678118654752f));
}

__device__ __forceinline__ void gld_lds16(const _Float16* g, _Float16* l) {
  __builtin_amdgcn_global_load_lds(
      (const __attribute__((address_space(1))) void*)g,
      (__attribute__((address_space(3))) void*)l, 16, 0, 0);
}

// ---------------------------------------------------------------- converts
__global__ void convert_f32_f16(const float* __restrict__ src,
                                _Float16* __restrict__ dst, int n4) {
  int i = blockIdx.x * blockDim.x + threadIdx.x;
  if (i >= n4) return;
  float4 v = ((const float4*)src)[i];
  half4v h;
  h[0] = (_Float16)v.x; h[1] = (_Float16)v.y;
  h[2] = (_Float16)v.z; h[3] = (_Float16)v.w;
  ((half4v*)dst)[i] = h;
}

// z=0: shared weight, z>=1: expert z-1.  src fp32 [R][C] -> dst fp16 [C][R]
__global__ void transpose_convert9(const float* __restrict__ srcSh,
                                   const float* __restrict__ srcEx,
                                   _Float16* __restrict__ dst, int R, int C) {
  const size_t msz = (size_t)R * C;
  const float* src = (blockIdx.z == 0) ? srcSh : srcEx + msz * (blockIdx.z - 1);
  _Float16* d = dst + msz * blockIdx.z;
  __shared__ float tile[32][33];
  int c0 = blockIdx.x * 32, r0 = blockIdx.y * 32;
  int tx = threadIdx.x, ty = threadIdx.y;   // block (32, 8)
#pragma unroll
  for (int i = 0; i < 4; ++i)
    tile[ty + i * 8][tx] = src[(size_t)(r0 + ty + i * 8) * C + c0 + tx];
  __syncthreads();
#pragma unroll
  for (int i = 0; i < 4; ++i)
    d[(size_t)(c0 + ty + i * 8) * R + r0 + tx] = (_Float16)tile[tx][ty + i * 8];
}

// ---------------------------------------------------------------- router
__global__ void router_kernel(const float* __restrict__ x,
                              const float* __restrict__ rw,
                              const float* __restrict__ rb,
                              int* __restrict__ sel_idx,
                              float* __restrict__ sel_w,
                              int* __restrict__ counts) {
  int lane = threadIdx.x & 63;
  int t = blockIdx.x * 4 + (threadIdx.x >> 6);
  const float* xr = x + (size_t)t * D_MODEL;
  float acc[N_EXP];
#pragma unroll
  for (int e = 0; e < N_EXP; ++e) acc[e] = 0.f;
  for (int k = lane; k < D_MODEL; k += 64) {
    float xv = xr[k];
    const float* w = rw + (size_t)k * N_EXP;
#pragma unroll
    for (int e = 0; e < N_EXP; ++e) acc[e] += xv * w[e];
  }
#pragma unroll
  for (int off = 32; off > 0; off >>= 1) {
#pragma unroll
    for (int e = 0; e < N_EXP; ++e)
      acc[e] += __shfl_down(acc[e], off, 64);
  }
  if (lane == 0) {
    float mx = -1e30f;
#pragma unroll
    for (int e = 0; e < N_EXP; ++e) { acc[e] += rb[e]; mx = fmaxf(mx, acc[e]); }
    float p[N_EXP], s = 0.f;
#pragma unroll
    for (int e = 0; e < N_EXP; ++e) { p[e] = expf(acc[e] - mx); s += p[e]; }
    float inv = 1.f / s;
#pragma unroll
    for (int e = 0; e < N_EXP; ++e) p[e] *= inv;
    int i0 = 0; float p0 = p[0];
#pragma unroll
    for (int e = 1; e < N_EXP; ++e) if (p[e] > p0) { p0 = p[e]; i0 = e; }
    int i1 = -1; float p1 = -1.f;
#pragma unroll
    for (int e = 0; e < N_EXP; ++e)
      if (e != i0 && p[e] > p1) { p1 = p[e]; i1 = e; }
    float s2 = p0 + p1 + 1e-9f;
    sel_idx[2 * t] = i0; sel_idx[2 * t + 1] = i1;
    sel_w[2 * t] = p0 / s2; sel_w[2 * t + 1] = p1 / s2;
    atomicAdd(&counts[i0 * 32], 1);
    atomicAdd(&counts[i1 * 32], 1);
  }
}

__global__ void scan_kernel(const int* __restrict__ counts,
                            int* __restrict__ offsets,
                            int* __restrict__ cursor) {
  if (threadIdx.x == 0) {
    int s = 0;
    for (int e = 0; e < N_EXP; ++e) {
      offsets[e] = s; cursor[e * 32] = s; s += counts[e * 32];
    }
    offsets[N_EXP] = s;
  }
}

__global__ void assign_kernel(const int* __restrict__ sel_idx,
                              int* __restrict__ cursor,
                              int* __restrict__ rows,
                              int* __restrict__ inv) {
  int t = blockIdx.x * blockDim.x + threadIdx.x;
  if (t >= T_TOK) return;
#pragma unroll
  for (int k = 0; k < 2; ++k) {
    int e = sel_idx[2 * t + k];
    int pos = atomicAdd(&cursor[e * 32], 1);
    rows[pos] = t;
    inv[2 * t + k] = pos;
  }
}

// ---------------------------------------------------------------- GEMM
// PHASE 1: FFN1  K=1024, N=4096.  z=0: H[m]=gelu(xb[m]@W1sh+b); z>=1:
//          H[T+offs+m]=gelu(xb[rows[offs+m]]@W1e+b).   fp16 stores.
// PHASE 2: FFN2  K=4096, N=1024.  z=0: out[m]=H[m]@W2sh+b (fp32); z>=1:
//          Yexp[offs+m]=H[T+offs+m]@W2e+b (fp32, gathered order).
// 128x128 tile, BK=64, 256 thr (2x2 waves of 64x64), XOR-swizzled staging.
// bounds(256,3): 170-reg cap — acc(64)+frags(16)+ptrs(~20)+misc fits, NO SPILL.
template <int PHASE>
__global__ __launch_bounds__(256, 3) void gemm_kernel(
    const _Float16* __restrict__ A, const _Float16* __restrict__ Wt,
    const float* __restrict__ biasSh, const float* __restrict__ biasEx,
    _Float16* __restrict__ Hout, float* __restrict__ out,
    float* __restrict__ Yexp, const int* __restrict__ rows,
    const int* __restrict__ counts, const int* __restrict__ offsets) {
  constexpr int K = (PHASE == 1) ? D_MODEL : D_FF;
  constexpr int N = (PHASE == 1) ? D_FF : D_MODEL;
  const int z = blockIdx.z;
  int M = T_TOK, offs = 0;
  if (z > 0) {
    M = counts[(z - 1) * 32];
    offs = offsets[z - 1];
    if ((int)blockIdx.y * 128 >= M) return;   // uniform early-exit
  }
  const int tid = threadIdx.x, lane = tid & 63, wid = tid >> 6;
  const int m0 = blockIdx.y * 128, n0 = blockIdx.x * 128;
  const _Float16* Wz = Wt + (size_t)z * N * K;

  __shared__ __align__(16) _Float16 As[128 * BK];  // [m][k], k-chunks swizzled
  __shared__ __align__(16) _Float16 Bs[128 * BK];  // [n][k]

  // staging: 16 chunk-groups of 8 rows x 128 B; wave w fills groups 4w..4w+3.
  // lane i -> row sub=i>>3 of the group, physical 16B slot p=i&7 holding
  // GLOBAL k-chunk g = p ^ sub  (XOR swizzle).
  const int sub = lane >> 3, pp = lane & 7, g = pp ^ sub;

  int r0i = m0 + (wid * 4 + 0) * 8 + sub;
  int r1i = m0 + (wid * 4 + 1) * 8 + sub;
  int r2i = m0 + (wid * 4 + 2) * 8 + sub;
  int r3i = m0 + (wid * 4 + 3) * 8 + sub;
  size_t gr0, gr1, gr2, gr3;
  if (z == 0) {
    gr0 = (size_t)r0i; gr1 = (size_t)r1i; gr2 = (size_t)r2i; gr3 = (size_t)r3i;
  } else if constexpr (PHASE == 1) {
    gr0 = (size_t)rows[offs + (r0i < M ? r0i : M - 1)];
    gr1 = (size_t)rows[offs + (r1i < M ? r1i : M - 1)];
    gr2 = (size_t)rows[offs + (r2i < M ? r2i : M - 1)];
    gr3 = (size_t)rows[offs + (r3i < M ? r3i : M - 1)];
  } else {
    gr0 = (size_t)(T_TOK + offs + (r0i < M ? r0i : M - 1));
    gr1 = (size_t)(T_TOK + offs + (r1i < M ? r1i : M - 1));
    gr2 = (size_t)(T_TOK + offs + (r2i < M ? r2i : M - 1));
    gr3 = (size_t)(T_TOK + offs + (r3i < M ? r3i : M - 1));
  }
  const _Float16* aS0 = A + gr0 * K + g * 8;
  const _Float16* aS1 = A + gr1 * K + g * 8;
  const _Float16* aS2 = A + gr2 * K + g * 8;
  const _Float16* aS3 = A + gr3 * K + g * 8;
  const _Float16* bS0 = Wz + (size_t)(n0 + (wid * 4 + 0) * 8 + sub) * K + g * 8;
  const _Float16* bS1 = Wz + (size_t)(n0 + (wid * 4 + 1) * 8 + sub) * K + g * 8;
  const _Float16* bS2 = Wz + (size_t)(n0 + (wid * 4 + 2) * 8 + sub) * K + g * 8;
  const _Float16* bS3 = Wz + (size_t)(n0 + (wid * 4 + 3) * 8 + sub) * K + g * 8;

  floatx4 acc[4][4] = {};
  const int wm = wid >> 1, wn = wid & 1;
  const int lr = lane & 15, qd = lane >> 4;

  for (int kt = 0; kt < K; kt += BK) {
    __syncthreads();
    gld_lds16(aS0, As + (wid * 4 + 0) * 512);
    gld_lds16(aS1, As + (wid * 4 + 1) * 512);
    gld_lds16(aS2, As + (wid * 4 + 2) * 512);
    gld_lds16(aS3, As + (wid * 4 + 3) * 512);
    gld_lds16(bS0, Bs + (wid * 4 + 0) * 512);
    gld_lds16(bS1, Bs + (wid * 4 + 1) * 512);
    gld_lds16(bS2, Bs + (wid * 4 + 2) * 512);
    gld_lds16(bS3, Bs + (wid * 4 + 3) * 512);
    aS0 += BK; aS1 += BK; aS2 += BK; aS3 += BK;
    bS0 += BK; bS1 += BK; bS2 += BK; bS3 += BK;
    asm volatile("s_waitcnt vmcnt(0)" ::: "memory");
    __syncthreads();
#pragma unroll
    for (int h = 0; h < 2; ++h) {
      half8 af[4], bf[4];
#pragma unroll
      for (int mi = 0; mi < 4; ++mi) {
        const int r = wm * 64 + mi * 16 + lr;
        const int slot = (h * 4 + qd) ^ (r & 7);
        af[mi] = *(const half8*)(As + r * BK + slot * 8);
      }
#pragma unroll
      for (int ni = 0; ni < 4; ++ni) {
        const int r = wn * 64 + ni * 16 + lr;
        const int slot = (h * 4 + qd) ^ (r & 7);
        bf[ni] = *(const half8*)(Bs + r * BK + slot * 8);
      }
#pragma unroll
      for (int mi = 0; mi < 4; ++mi)
#pragma unroll
        for (int ni = 0; ni < 4; ++ni)
          acc[mi][ni] = __builtin_amdgcn_mfma_f32_16x16x32_f16(
              af[mi], bf[ni], acc[mi][ni], 0, 0, 0);
    }
  }

  // epilogue: C/D layout col=lane&15, row=quad*4+reg (R1-verified)
  const float* be = (z == 0) ? biasSh : biasEx + (size_t)(z - 1) * N;
#pragma unroll
  for (int mi = 0; mi < 4; ++mi) {
#pragma unroll
    for (int ni = 0; ni < 4; ++ni) {
      floatx4 v = acc[mi][ni];
#pragma unroll
      for (int r4 = 0; r4 < 4; ++r4) {
        const int lrow = m0 + wm * 64 + mi * 16 + qd * 4 + r4;  // row in segment
        const int col = n0 + wn * 64 + ni * 16 + lr;
        const float val = v[r4] + be[col];
        if constexpr (PHASE == 1) {
          if (z == 0) {
            Hout[(size_t)lrow * N + col] = (_Float16)gelu_exact(val);
          } else if (lrow < M) {
            Hout[(size_t)(T_TOK + offs + lrow) * N + col] =
                (_Float16)gelu_exact(val);
          }
        } else {
          if (z == 0) {
            out[(size_t)lrow * N + col] = val;
          } else if (lrow < M) {
            Yexp[(size_t)(offs + lrow) * N + col] = val;
          }
        }
      }
    }
  }
}

// ---------------------------------------------------------------- combine
// out[t] = out[t] (shared FFN2) + w0*Yexp[p0] + w1*Yexp[p1]
__global__ void combine_kernel(float* __restrict__ out,
                               const float* __restrict__ Yexp,
                               const int* __restrict__ inv,
                               const float* __restrict__ selw) {
  const int t = blockIdx.x;
  const int c = threadIdx.x * 4;
  const int p0 = inv[2 * t], p1 = inv[2 * t + 1];
  const float w0 = selw[2 * t], w1 = selw[2 * t + 1];
  float4 o = *(float4*)(out + (size_t)t * D_MODEL + c);
  const float4 a = *(const float4*)(Yexp + (size_t)p0 * D_MODEL + c);
  const float4 b = *(const float4*)(Yexp + (size_t)p1 * D_MODEL + c);
  o.x += w0 * a.x + w1 * b.x;
  o.y += w0 * a.y + w1 * b.y;
  o.z += w0 * a.z + w1 * b.z;
  o.w += w0 * a.w + w1 * b.w;
  *(float4*)(out + (size_t)t * D_MODEL + c) = o;
}

// ---------------------------------------------------------------- launch
extern "C" void kernel_launch(void* const* d_in, const int* in_sizes, int n_in,
                              void* d_out, int out_size, void* d_ws,
                              size_t ws_size, hipStream_t stream) {
  const float* x   = (const float*)d_in[0];
  const float* sw1 = (const float*)d_in[1];
  const float* sb1 = (const float*)d_in[2];
  const float* sw2 = (const float*)d_in[3];
  const float* sb2 = (const float*)d_in[4];
  const float* rw  = (const float*)d_in[5];
  const float* rb  = (const float*)d_in[6];
  const float* ew1 = (const float*)d_in[7];
  const float* eb1 = (const float*)d_in[8];
  const float* ew2 = (const float*)d_in[9];
  const float* eb2 = (const float*)d_in[10];
  float* out = (float*)d_out;

  char* ws = (char*)d_ws;
  size_t off = 0;
  auto alloc = [&](size_t bytes) {
    void* p = ws + off;
    off += (bytes + 255) & ~(size_t)255;
    return p;
  };
  _Float16* xb  = (_Float16*)alloc((size_t)T_TOK * D_MODEL * 2);        // 16 MB
  _Float16* w2t = (_Float16*)alloc((size_t)9 * D_MODEL * D_FF * 2);     // 72 MB
  _Float16* H   = (_Float16*)alloc((size_t)3 * T_TOK * D_FF * 2);       // 201 MB
  _Float16* w1t = (_Float16*)alloc((size_t)9 * D_FF * D_MODEL * 2);     // 72 MB
  float* Yexp   = (float*)w1t;  // alias: w1t dead after FFN1, Yexp 67 MB
  int*   sel_idx = (int*)alloc((size_t)T_TOK * 2 * 4);
  float* sel_w   = (float*)alloc((size_t)T_TOK * 2 * 4);
  int*   rows    = (int*)alloc((size_t)2 * T_TOK * 4);
  int*   inv     = (int*)alloc((size_t)2 * T_TOK * 4);
  int*   counts  = (int*)alloc(N_EXP * 32 * 4);
  int*   offsets = (int*)alloc(16 * 4);
  int*   cursor  = (int*)alloc(N_EXP * 32 * 4);
  (void)ws_size; (void)in_sizes; (void)n_in; (void)out_size;

  hipMemsetAsync(counts, 0, N_EXP * 32 * 4, stream);

  convert_f32_f16<<<(T_TOK * D_MODEL / 4 + 255) / 256, 256, 0, stream>>>(
      x, xb, T_TOK * D_MODEL / 4);
  dim3 tb(32, 8);
  // W1: [1024][4096] -> [4096][1024];  W2: [4096][1024] -> [1024][4096]
  transpose_convert9<<<dim3(D_FF / 32, D_MODEL / 32, 9), tb, 0, stream>>>(
      sw1, ew1, w1t, D_MODEL, D_FF);
  transpose_convert9<<<dim3(D_MODEL / 32, D_FF / 32, 9), tb, 0, stream>>>(
      sw2, ew2, w2t, D_FF, D_MODEL);

  router_kernel<<<T_TOK / 4, 256, 0, stream>>>(x, rw, rb, sel_idx, sel_w, counts);
  scan_kernel<<<1, 64, 0, stream>>>(counts, offsets, cursor);
  assign_kernel<<<T_TOK / 256, 256, 0, stream>>>(sel_idx, cursor, rows, inv);

  gemm_kernel<1><<<dim3(D_FF / 128, T_TOK / 128, 9), 256, 0, stream>>>(
      xb, w1t, sb1, eb1, H, nullptr, nullptr, rows, counts, offsets);
  gemm_kernel<2><<<dim3(D_MODEL / 128, T_TOK / 128, 9), 256, 0, stream>>>(
      H, w2t, sb2, eb2, nullptr, out, Yexp, rows, counts, offsets);

  combine_kernel<<<T_TOK, 256, 0, stream>>>(out, Yexp, inv, sel_w);
}